// Round 1
// 341.186 us; speedup vs baseline: 1.3997x; 1.3997x over previous
//
#include <hip/hip_runtime.h>

#define KG 256      // gaussians
#define DD 12       // feature dim
#define HH 32       // hidden
#define CC 9        // output channels
#define TPB 64      // one wave per block; thread = probe
#define KT 32       // k-tile staged in LDS per wave for coalesced w stores
#define TSTR 36     // tile row stride in floats: 144 B (16B-aligned, spreads banks)

// ---------------- precompute: per-gaussian coefficient row ----------------
// Ct[k*32 + f]:
//  [0..8]  quadratic-form poly coeffs on {xx,yy,zz,xy,xz,yz,x,y,z}, pre-scaled
//          by -0.5*log2(e)
//  [9]     const term (pre-scaled)
//  [10..12] -2*mu   [13] |mu|^2   [14] r^2 = (3*smax)^2   [15] pad
//  [16..27] F[k][0..11]           [28..31] pad
// Row-per-k layout so the main kernel's uniform k-loop reads become
// s_load_dwordx16 streams (scalar pipe, co-issues with VALU).
__global__ __launch_bounds__(256) void gp_pre(
    const float* __restrict__ mu, const float* __restrict__ log_s,
    const float* __restrict__ q, const float* __restrict__ F,
    float* __restrict__ Ct) {
  int k = threadIdx.x;
  if (k >= KG) return;
  float qw = q[k*4+0], qx = q[k*4+1], qy = q[k*4+2], qz = q[k*4+3];
  float nrm = sqrtf(qw*qw + qx*qx + qy*qy + qz*qz);
  float isn = 1.0f / (nrm + 1e-8f);
  qw *= isn; qx *= isn; qy *= isn; qz *= isn;
  float R00 = 1.f - 2.f*(qy*qy + qz*qz);
  float R01 = 2.f*(qx*qy - qw*qz);
  float R02 = 2.f*(qx*qz + qw*qy);
  float R10 = 2.f*(qx*qy + qw*qz);
  float R11 = 1.f - 2.f*(qx*qx + qz*qz);
  float R12 = 2.f*(qy*qz - qw*qx);
  float R20 = 2.f*(qx*qz - qw*qy);
  float R21 = 2.f*(qy*qz + qw*qx);
  float R22 = 1.f - 2.f*(qx*qx + qy*qy);
  float s0 = expf(log_s[k*3+0]);
  float s1 = expf(log_s[k*3+1]);
  float s2 = expf(log_s[k*3+2]);
  float si0 = 1.f/(s0*s0 + 1e-8f);
  float si1 = 1.f/(s1*s1 + 1e-8f);
  float si2 = 1.f/(s2*s2 + 1e-8f);
  float P00 = R00*si0*R00 + R01*si1*R01 + R02*si2*R02;
  float P01 = R00*si0*R10 + R01*si1*R11 + R02*si2*R12;
  float P02 = R00*si0*R20 + R01*si1*R21 + R02*si2*R22;
  float P11 = R10*si0*R10 + R11*si1*R11 + R12*si2*R12;
  float P12 = R10*si0*R20 + R11*si1*R21 + R12*si2*R22;
  float P22 = R20*si0*R20 + R21*si1*R21 + R22*si2*R22;
  float m0 = mu[k*3+0], m1 = mu[k*3+1], m2 = mu[k*3+2];
  float b0 = P00*m0 + P01*m1 + P02*m2;
  float b1v = P01*m0 + P11*m1 + P12*m2;
  float b2v = P02*m0 + P12*m1 + P22*m2;
  float cterm = m0*b0 + m1*b1v + m2*b2v;
  const float f = -0.7213475204444817f;  // -0.5*log2(e)
  float* c = Ct + k*32;
  c[0] = f*P00;  c[1] = f*P11;  c[2] = f*P22;
  c[3] = 2.f*f*P01;  c[4] = 2.f*f*P02;  c[5] = 2.f*f*P12;
  c[6] = -2.f*f*b0;  c[7] = -2.f*f*b1v; c[8] = -2.f*f*b2v;
  c[9] = f*cterm;
  c[10] = -2.f*m0;  c[11] = -2.f*m1;  c[12] = -2.f*m2;
  c[13] = m0*m0 + m1*m1 + m2*m2;
  float smax = fmaxf(s0, fmaxf(s1, s2));
  c[14] = (3.f*smax)*(3.f*smax);
  c[15] = 0.f;
  #pragma unroll
  for (int d = 0; d < DD; ++d) c[16+d] = F[k*DD + d];
  c[28] = c[29] = c[30] = c[31] = 0.f;
}

// gated unnormalized gaussian for one (probe, k). Same fma-chain order as the
// previously-passing kernel (error characteristics preserved). exp2 via the
// native op (v_exp_f32); differs from exp2f only on denormal outputs.
__device__ __forceinline__ float gauss_eval(
    const float* __restrict__ c,
    float xx, float yy, float zz, float xy, float xz, float yz,
    float x, float y, float z, float pp) {
  float tp = fmaf(c[0], xx, c[9]);
  tp = fmaf(c[1], yy, tp);
  tp = fmaf(c[2], zz, tp);
  tp = fmaf(c[3], xy, tp);
  tp = fmaf(c[4], xz, tp);
  tp = fmaf(c[5], yz, tp);
  tp = fmaf(c[6], x, tp);
  tp = fmaf(c[7], y, tp);
  tp = fmaf(c[8], z, tp);
  float d2 = pp + c[13];
  d2 = fmaf(c[10], x, d2);
  d2 = fmaf(c[11], y, d2);
  d2 = fmaf(c[12], z, d2);
  float e = __builtin_amdgcn_exp2f(tp);
  return (d2 < c[14]) ? e : 0.0f;
}

// ---------------- main: thread = probe, everything register-resident --------
// pass A: denom + unnormalized latent in VGPRs (coeffs stream on scalar pipe)
// epilogue: latent store, fused MLP, sh store (all lanes active)
// pass B: recompute g, normalize, stage [64][KT] per-wave LDS tile, store
//         w coalesced (8 fully-covered 128B lines per store instruction)
__global__ __launch_bounds__(TPB) void gp_main(
    const float* __restrict__ pos, const float* __restrict__ Ct,
    const float* __restrict__ W1, const float* __restrict__ b1,
    const float* __restrict__ W2, const float* __restrict__ b2,
    float* __restrict__ sh_out, float* __restrict__ lat_out,
    float* __restrict__ w_out, int N) {
  __shared__ float tile[TPB * TSTR];   // 9216 B
  const int lane = threadIdx.x;
  const int pbase = blockIdx.x * TPB;
  const int p = pbase + lane;
  const bool valid = (p < N);
  const int pc = valid ? p : (N - 1);
  const float x = pos[pc*3+0], y = pos[pc*3+1], z = pos[pc*3+2];
  const float xx = x*x, yy = y*y, zz = z*z;
  const float xy = x*y, xz = x*z, yz = y*z;
  const float pp = xx + yy + zz;

  // ---- pass A: denominator + unnormalized latent ----
  float lat[DD];
  #pragma unroll
  for (int j = 0; j < DD; ++j) lat[j] = 0.0f;
  float denom = 1e-8f;
  #pragma unroll 4
  for (int k = 0; k < KG; ++k) {
    const float* c = Ct + (k << 5);
    float g = gauss_eval(c, xx, yy, zz, xy, xz, yz, x, y, z, pp);
    denom += g;
    #pragma unroll
    for (int j = 0; j < DD; ++j) lat[j] = fmaf(g, c[16+j], lat[j]);
  }
  const float inv = 1.0f / denom;

  // ---- latent store (p*48B: 16B-aligned float4s, contiguous union) ----
  float lf[DD];
  #pragma unroll
  for (int j = 0; j < DD; ++j) lf[j] = lat[j] * inv;
  if (valid) {
    float4* lo = (float4*)(lat_out + (size_t)p * DD);
    lo[0] = make_float4(lf[0], lf[1], lf[2],  lf[3]);
    lo[1] = make_float4(lf[4], lf[5], lf[6],  lf[7]);
    lo[2] = make_float4(lf[8], lf[9], lf[10], lf[11]);
  }

  // ---- fused MLP: every lane owns its probe; W1/b1/W2/b2 uniform -> s_load ----
  float h[HH];
  #pragma unroll
  for (int j = 0; j < HH; ++j) h[j] = b1[j];
  #pragma unroll
  for (int i = 0; i < DD; ++i) {
    const float v = lf[i];
    #pragma unroll
    for (int j = 0; j < HH; ++j) h[j] = fmaf(v, W1[i*HH + j], h[j]);
  }
  #pragma unroll
  for (int j = 0; j < HH; ++j) h[j] = fmaf(x, W1[12*HH + j], h[j]);
  #pragma unroll
  for (int j = 0; j < HH; ++j) h[j] = fmaf(y, W1[13*HH + j], h[j]);
  #pragma unroll
  for (int j = 0; j < HH; ++j) h[j] = fmaf(z, W1[14*HH + j], h[j]);
  float o[CC];
  #pragma unroll
  for (int c2 = 0; c2 < CC; ++c2) o[c2] = b2[c2];
  #pragma unroll
  for (int j = 0; j < HH; ++j) {
    const float a = fmaxf(h[j], 0.0f);
    #pragma unroll
    for (int c2 = 0; c2 < CC; ++c2) o[c2] = fmaf(a, W2[j*CC + c2], o[c2]);
  }
  if (valid) {
    float* so = sh_out + (size_t)p * CC;
    #pragma unroll
    for (int c2 = 0; c2 < CC; ++c2) so[c2] = o[c2];
  }

  // ---- pass B: normalized w, per-wave LDS tile, coalesced stores ----
  #pragma unroll 1
  for (int k0 = 0; k0 < KG; k0 += KT) {
    #pragma unroll
    for (int kq = 0; kq < KT; kq += 4) {
      float wv[4];
      #pragma unroll
      for (int u = 0; u < 4; ++u) {
        const float* c = Ct + ((k0 + kq + u) << 5);
        wv[u] = gauss_eval(c, xx, yy, zz, xy, xz, yz, x, y, z, pp) * inv;
      }
      // row stride 36 floats: lane bank-start = 4*lane mod 32 -> at the
      // 8-cycle b128 floor, 16B-aligned
      *(float4*)&tile[lane*TSTR + kq] = make_float4(wv[0], wv[1], wv[2], wv[3]);
    }
    __syncthreads();
    // 8 rows x 128B per store instruction, rows fully covered -> L2-friendly
    #pragma unroll
    for (int r4 = 0; r4 < 8; ++r4) {
      const int row = r4*8 + (lane >> 3);
      const int col = (lane & 7) * 4;
      const float4 v = *(const float4*)&tile[row*TSTR + col];
      const int gp2 = pbase + row;
      if (gp2 < N)
        *(float4*)&w_out[(size_t)gp2 * KG + k0 + col] = v;
    }
    __syncthreads();
  }
}

extern "C" void kernel_launch(void* const* d_in, const int* in_sizes, int n_in,
                              void* d_out, int out_size, void* d_ws, size_t ws_size,
                              hipStream_t stream) {
  const float* probe_pos = (const float*)d_in[0];
  const float* mu        = (const float*)d_in[1];
  const float* log_s     = (const float*)d_in[2];
  const float* q         = (const float*)d_in[3];
  const float* F         = (const float*)d_in[4];
  const float* W1        = (const float*)d_in[5];
  const float* b1        = (const float*)d_in[6];
  const float* W2        = (const float*)d_in[7];
  const float* b2        = (const float*)d_in[8];
  const int N = in_sizes[0] / 3;

  float* Ct = (float*)d_ws;                    // 256*32 floats = 32 KB
  float* sh_out  = (float*)d_out;              // [N,9]
  float* lat_out = sh_out + (size_t)N*CC;      // [N,12]
  float* w_out   = lat_out + (size_t)N*DD;     // [N,256]

  gp_pre<<<1, 256, 0, stream>>>(mu, log_s, q, F, Ct);
  const int nb = (N + TPB - 1) / TPB;
  gp_main<<<nb, TPB, 0, stream>>>(probe_pos, Ct, W1, b1, W2, b2,
                                  sh_out, lat_out, w_out, N);
}

// Round 2
// 314.996 us; speedup vs baseline: 1.5161x; 1.0831x over previous
//
#include <hip/hip_runtime.h>

#define KG 256      // gaussians
#define DD 12       // feature dim
#define HH 32       // hidden
#define CC 9        // output channels
#define TPB 256     // 4 waves; thread = probe for pass A / MLP

// ---------------- precompute: per-gaussian coefficient row ----------------
// Ct[k*32 + f]:
//  [0..8]  quadratic-form poly coeffs on {xx,yy,zz,xy,xz,yz,x,y,z}, pre-scaled
//          by -0.5*log2(e)
//  [9]     const term (pre-scaled)
//  [10..12] -2*mu   [13] |mu|^2   [14] r^2 = (3*smax)^2   [15] pad
//  [16..27] F[k][0..11]           [28..31] pad
// Row-per-k so the pass-A uniform k-loop reads become s_load_dwordx16
// streams (scalar pipe, co-issues with VALU).
__global__ __launch_bounds__(256) void gp_pre(
    const float* __restrict__ mu, const float* __restrict__ log_s,
    const float* __restrict__ q, const float* __restrict__ F,
    float* __restrict__ Ct) {
  int k = threadIdx.x;
  if (k >= KG) return;
  float qw = q[k*4+0], qx = q[k*4+1], qy = q[k*4+2], qz = q[k*4+3];
  float nrm = sqrtf(qw*qw + qx*qx + qy*qy + qz*qz);
  float isn = 1.0f / (nrm + 1e-8f);
  qw *= isn; qx *= isn; qy *= isn; qz *= isn;
  float R00 = 1.f - 2.f*(qy*qy + qz*qz);
  float R01 = 2.f*(qx*qy - qw*qz);
  float R02 = 2.f*(qx*qz + qw*qy);
  float R10 = 2.f*(qx*qy + qw*qz);
  float R11 = 1.f - 2.f*(qx*qx + qz*qz);
  float R12 = 2.f*(qy*qz - qw*qx);
  float R20 = 2.f*(qx*qz - qw*qy);
  float R21 = 2.f*(qy*qz + qw*qx);
  float R22 = 1.f - 2.f*(qx*qx + qy*qy);
  float s0 = expf(log_s[k*3+0]);
  float s1 = expf(log_s[k*3+1]);
  float s2 = expf(log_s[k*3+2]);
  float si0 = 1.f/(s0*s0 + 1e-8f);
  float si1 = 1.f/(s1*s1 + 1e-8f);
  float si2 = 1.f/(s2*s2 + 1e-8f);
  float P00 = R00*si0*R00 + R01*si1*R01 + R02*si2*R02;
  float P01 = R00*si0*R10 + R01*si1*R11 + R02*si2*R12;
  float P02 = R00*si0*R20 + R01*si1*R21 + R02*si2*R22;
  float P11 = R10*si0*R10 + R11*si1*R11 + R12*si2*R12;
  float P12 = R10*si0*R20 + R11*si1*R21 + R12*si2*R22;
  float P22 = R20*si0*R20 + R21*si1*R21 + R22*si2*R22;
  float m0 = mu[k*3+0], m1 = mu[k*3+1], m2 = mu[k*3+2];
  float b0 = P00*m0 + P01*m1 + P02*m2;
  float b1v = P01*m0 + P11*m1 + P12*m2;
  float b2v = P02*m0 + P12*m1 + P22*m2;
  float cterm = m0*b0 + m1*b1v + m2*b2v;
  const float f = -0.7213475204444817f;  // -0.5*log2(e)
  float* c = Ct + k*32;
  c[0] = f*P00;  c[1] = f*P11;  c[2] = f*P22;
  c[3] = 2.f*f*P01;  c[4] = 2.f*f*P02;  c[5] = 2.f*f*P12;
  c[6] = -2.f*f*b0;  c[7] = -2.f*f*b1v; c[8] = -2.f*f*b2v;
  c[9] = f*cterm;
  c[10] = -2.f*m0;  c[11] = -2.f*m1;  c[12] = -2.f*m2;
  c[13] = m0*m0 + m1*m1 + m2*m2;
  float smax = fmaxf(s0, fmaxf(s1, s2));
  c[14] = (3.f*smax)*(3.f*smax);
  c[15] = 0.f;
  #pragma unroll
  for (int d = 0; d < DD; ++d) c[16+d] = F[k*DD + d];
  c[28] = c[29] = c[30] = c[31] = 0.f;
}

// gated unnormalized gaussian for one (probe, k). Same fma-chain order as the
// previously-passing kernel (error characteristics preserved). exp2 via the
// native op (v_exp_f32); differs from exp2f only on denormal outputs.
__device__ __forceinline__ float gauss_eval(
    const float* __restrict__ c,
    float xx, float yy, float zz, float xy, float xz, float yz,
    float x, float y, float z, float pp) {
  float tp = fmaf(c[0], xx, c[9]);
  tp = fmaf(c[1], yy, tp);
  tp = fmaf(c[2], zz, tp);
  tp = fmaf(c[3], xy, tp);
  tp = fmaf(c[4], xz, tp);
  tp = fmaf(c[5], yz, tp);
  tp = fmaf(c[6], x, tp);
  tp = fmaf(c[7], y, tp);
  tp = fmaf(c[8], z, tp);
  float d2 = pp + c[13];
  d2 = fmaf(c[10], x, d2);
  d2 = fmaf(c[11], y, d2);
  d2 = fmaf(c[12], z, d2);
  float e = __builtin_amdgcn_exp2f(tp);
  return (d2 < c[14]) ? e : 0.0f;
}

// ---------------- main ------------------------------------------------------
// pass A (thread = probe): denom + unnormalized latent in VGPRs; coefficient
//   rows stream uniformly on the scalar pipe.  Then latent store + fused MLP.
// pass B (lane = 4 gaussians, wave iterates its 64 probes): each lane holds
//   coeffs of k=lane*4..+3 in registers; per probe, one 16B broadcast
//   ds_read_b128 of (x,y,z,inv), 4 gauss evals, one coalesced
//   global_store_dwordx4 (lanes cover 1KB contiguous).  No tiles, no
//   per-tile barriers, no transpose.
__global__ __launch_bounds__(TPB, 4) void gp_main(
    const float* __restrict__ pos, const float* __restrict__ Ct,
    const float* __restrict__ W1, const float* __restrict__ b1,
    const float* __restrict__ W2, const float* __restrict__ b2,
    float* __restrict__ sh_out, float* __restrict__ lat_out,
    float* __restrict__ w_out, int N) {
  __shared__ float pxyzi[TPB][4];      // 4 KB: per-probe (x,y,z,inv)
  const int tid = threadIdx.x;
  const int pbase = blockIdx.x * TPB;
  const int p = pbase + tid;
  const bool valid = (p < N);
  const int pc = valid ? p : (N - 1);
  const float x = pos[pc*3+0], y = pos[pc*3+1], z = pos[pc*3+2];
  const float xx = x*x, yy = y*y, zz = z*z;
  const float xy = x*y, xz = x*z, yz = y*z;
  const float pp = xx + yy + zz;

  // ---- pass A: denominator + unnormalized latent ----
  float lat[DD];
  #pragma unroll
  for (int j = 0; j < DD; ++j) lat[j] = 0.0f;
  float denom = 1e-8f;
  #pragma unroll 4
  for (int k = 0; k < KG; ++k) {
    const float* c = Ct + (k << 5);
    float g = gauss_eval(c, xx, yy, zz, xy, xz, yz, x, y, z, pp);
    denom += g;
    #pragma unroll
    for (int j = 0; j < DD; ++j) lat[j] = fmaf(g, c[16+j], lat[j]);
  }
  const float inv = 1.0f / denom;

  // publish (x,y,z,inv) for pass B's broadcast reads
  *(float4*)pxyzi[tid] = make_float4(x, y, z, inv);

  // ---- latent store (p*48B: 16B-aligned float4s, contiguous union) ----
  float lf[DD];
  #pragma unroll
  for (int j = 0; j < DD; ++j) lf[j] = lat[j] * inv;
  if (valid) {
    float4* lo = (float4*)(lat_out + (size_t)p * DD);
    lo[0] = make_float4(lf[0], lf[1], lf[2],  lf[3]);
    lo[1] = make_float4(lf[4], lf[5], lf[6],  lf[7]);
    lo[2] = make_float4(lf[8], lf[9], lf[10], lf[11]);
  }

  // ---- fused MLP: every lane owns its probe; W1/b1/W2/b2 uniform -> s_load ----
  {
    float h[HH];
    #pragma unroll
    for (int j = 0; j < HH; ++j) h[j] = b1[j];
    #pragma unroll
    for (int i = 0; i < DD; ++i) {
      const float v = lf[i];
      #pragma unroll
      for (int j = 0; j < HH; ++j) h[j] = fmaf(v, W1[i*HH + j], h[j]);
    }
    #pragma unroll
    for (int j = 0; j < HH; ++j) h[j] = fmaf(x, W1[12*HH + j], h[j]);
    #pragma unroll
    for (int j = 0; j < HH; ++j) h[j] = fmaf(y, W1[13*HH + j], h[j]);
    #pragma unroll
    for (int j = 0; j < HH; ++j) h[j] = fmaf(z, W1[14*HH + j], h[j]);
    float o[CC];
    #pragma unroll
    for (int c2 = 0; c2 < CC; ++c2) o[c2] = b2[c2];
    #pragma unroll
    for (int j = 0; j < HH; ++j) {
      const float a = fmaxf(h[j], 0.0f);
      #pragma unroll
      for (int c2 = 0; c2 < CC; ++c2) o[c2] = fmaf(a, W2[j*CC + c2], o[c2]);
    }
    if (valid) {
      float* so = sh_out + (size_t)p * CC;
      #pragma unroll
      for (int c2 = 0; c2 < CC; ++c2) so[c2] = o[c2];
    }
  }

  // ---- pass B: lane owns gaussians k = lane*4 .. lane*4+3 ----
  const int lane = tid & 63;
  const int wbase = tid & ~63;       // this wave's first local probe
  // load the 15 live coeffs (+pad) of each owned gaussian into registers
  float cb[4][16];
  #pragma unroll
  for (int u = 0; u < 4; ++u) {
    const float4* r = (const float4*)(Ct + (((lane << 2) + u) << 5));
    *(float4*)&cb[u][0]  = r[0];
    *(float4*)&cb[u][4]  = r[1];
    *(float4*)&cb[u][8]  = r[2];
    *(float4*)&cb[u][12] = r[3];
  }
  __syncthreads();                   // pxyzi visible to all lanes

  #pragma unroll 2
  for (int pi = 0; pi < 64; ++pi) {
    const int lp = wbase + pi;       // local probe index (this wave's own)
    const float4 b = *(const float4*)pxyzi[lp];   // broadcast read
    const float bx = b.x, by = b.y, bz = b.z, binv = b.w;
    const float bxx = bx*bx, byy = by*by, bzz = bz*bz;
    const float bxy = bx*by, bxz = bx*bz, byz = by*bz;
    const float bpp = bxx + byy + bzz;
    float wv[4];
    #pragma unroll
    for (int u = 0; u < 4; ++u)
      wv[u] = gauss_eval(cb[u], bxx, byy, bzz, bxy, bxz, byz,
                         bx, by, bz, bpp) * binv;
    const int gp2 = pbase + lp;
    if (gp2 < N)
      *(float4*)&w_out[(size_t)gp2 * KG + (lane << 2)] =
          make_float4(wv[0], wv[1], wv[2], wv[3]);
  }
}

extern "C" void kernel_launch(void* const* d_in, const int* in_sizes, int n_in,
                              void* d_out, int out_size, void* d_ws, size_t ws_size,
                              hipStream_t stream) {
  const float* probe_pos = (const float*)d_in[0];
  const float* mu        = (const float*)d_in[1];
  const float* log_s     = (const float*)d_in[2];
  const float* q         = (const float*)d_in[3];
  const float* F         = (const float*)d_in[4];
  const float* W1        = (const float*)d_in[5];
  const float* b1        = (const float*)d_in[6];
  const float* W2        = (const float*)d_in[7];
  const float* b2        = (const float*)d_in[8];
  const int N = in_sizes[0] / 3;

  float* Ct = (float*)d_ws;                    // 256*32 floats = 32 KB
  float* sh_out  = (float*)d_out;              // [N,9]
  float* lat_out = sh_out + (size_t)N*CC;      // [N,12]
  float* w_out   = lat_out + (size_t)N*DD;     // [N,256]

  gp_pre<<<1, 256, 0, stream>>>(mu, log_s, q, F, Ct);
  const int nb = (N + TPB - 1) / TPB;
  gp_main<<<nb, TPB, 0, stream>>>(probe_pos, Ct, W1, b1, W2, b2,
                                  sh_out, lat_out, w_out, N);
}

// Round 3
// 288.916 us; speedup vs baseline: 1.6530x; 1.0903x over previous
//
#include <hip/hip_runtime.h>

#define KG 256      // gaussians
#define DD 12       // feature dim
#define HH 32       // hidden
#define CC 9        // output channels
#define TPB 256     // 4 waves
#define PPB 64      // probes per block (N = 3125 * 64 exactly)
#define KSPL 4      // k-split across the 4 waves
#define KPT 64      // gaussians per thread in pass A (KG/KSPL)
#define PSTR 16     // partials row stride (floats): aligned b128 writes

// ---------------- precompute: per-gaussian coefficient row ----------------
// Ct[k*32 + f]:
//  [0..8]  quadratic-form poly coeffs on {xx,yy,zz,xy,xz,yz,x,y,z}, pre-scaled
//          by -0.5*log2(e)
//  [9]     const term (pre-scaled)
//  [10..12] -2*mu   [13] |mu|^2   [14] r^2 = (3*smax)^2   [15] pad
//  [16..27] F[k][0..11]           [28..31] pad
__global__ __launch_bounds__(256) void gp_pre(
    const float* __restrict__ mu, const float* __restrict__ log_s,
    const float* __restrict__ q, const float* __restrict__ F,
    float* __restrict__ Ct) {
  int k = threadIdx.x;
  if (k >= KG) return;
  float qw = q[k*4+0], qx = q[k*4+1], qy = q[k*4+2], qz = q[k*4+3];
  float nrm = sqrtf(qw*qw + qx*qx + qy*qy + qz*qz);
  float isn = 1.0f / (nrm + 1e-8f);
  qw *= isn; qx *= isn; qy *= isn; qz *= isn;
  float R00 = 1.f - 2.f*(qy*qy + qz*qz);
  float R01 = 2.f*(qx*qy - qw*qz);
  float R02 = 2.f*(qx*qz + qw*qy);
  float R10 = 2.f*(qx*qy + qw*qz);
  float R11 = 1.f - 2.f*(qx*qx + qz*qz);
  float R12 = 2.f*(qy*qz - qw*qx);
  float R20 = 2.f*(qx*qz - qw*qy);
  float R21 = 2.f*(qy*qz + qw*qx);
  float R22 = 1.f - 2.f*(qx*qx + qy*qy);
  float s0 = expf(log_s[k*3+0]);
  float s1 = expf(log_s[k*3+1]);
  float s2 = expf(log_s[k*3+2]);
  float si0 = 1.f/(s0*s0 + 1e-8f);
  float si1 = 1.f/(s1*s1 + 1e-8f);
  float si2 = 1.f/(s2*s2 + 1e-8f);
  float P00 = R00*si0*R00 + R01*si1*R01 + R02*si2*R02;
  float P01 = R00*si0*R10 + R01*si1*R11 + R02*si2*R12;
  float P02 = R00*si0*R20 + R01*si1*R21 + R02*si2*R22;
  float P11 = R10*si0*R10 + R11*si1*R11 + R12*si2*R12;
  float P12 = R10*si0*R20 + R11*si1*R21 + R12*si2*R22;
  float P22 = R20*si0*R20 + R21*si1*R21 + R22*si2*R22;
  float m0 = mu[k*3+0], m1 = mu[k*3+1], m2 = mu[k*3+2];
  float b0 = P00*m0 + P01*m1 + P02*m2;
  float b1v = P01*m0 + P11*m1 + P12*m2;
  float b2v = P02*m0 + P12*m1 + P22*m2;
  float cterm = m0*b0 + m1*b1v + m2*b2v;
  const float f = -0.7213475204444817f;  // -0.5*log2(e)
  float* c = Ct + k*32;
  c[0] = f*P00;  c[1] = f*P11;  c[2] = f*P22;
  c[3] = 2.f*f*P01;  c[4] = 2.f*f*P02;  c[5] = 2.f*f*P12;
  c[6] = -2.f*f*b0;  c[7] = -2.f*f*b1v; c[8] = -2.f*f*b2v;
  c[9] = f*cterm;
  c[10] = -2.f*m0;  c[11] = -2.f*m1;  c[12] = -2.f*m2;
  c[13] = m0*m0 + m1*m1 + m2*m2;
  float smax = fmaxf(s0, fmaxf(s1, s2));
  c[14] = (3.f*smax)*(3.f*smax);
  c[15] = 0.f;
  #pragma unroll
  for (int d = 0; d < DD; ++d) c[16+d] = F[k*DD + d];
  c[28] = c[29] = c[30] = c[31] = 0.f;
}

// gated unnormalized gaussian for one (probe, k). Same fma-chain order across
// rounds (error characteristics preserved). exp2 via native v_exp_f32.
__device__ __forceinline__ float gauss_eval(
    const float* __restrict__ c,
    float xx, float yy, float zz, float xy, float xz, float yz,
    float x, float y, float z, float pp) {
  float tp = fmaf(c[0], xx, c[9]);
  tp = fmaf(c[1], yy, tp);
  tp = fmaf(c[2], zz, tp);
  tp = fmaf(c[3], xy, tp);
  tp = fmaf(c[4], xz, tp);
  tp = fmaf(c[5], yz, tp);
  tp = fmaf(c[6], x, tp);
  tp = fmaf(c[7], y, tp);
  tp = fmaf(c[8], z, tp);
  float d2 = pp + c[13];
  d2 = fmaf(c[10], x, d2);
  d2 = fmaf(c[11], y, d2);
  d2 = fmaf(c[12], z, d2);
  float e = __builtin_amdgcn_exp2f(tp);
  return (d2 < c[14]) ? e : 0.0f;
}

// ---------------- main ------------------------------------------------------
// Block = 256 threads / 64 probes.  Pass A is k-split across the 4 waves
// (thread = (probe lane, k-group wave), 64 gaussians each) -> 12500 waves
// total (12.2/SIMD) instead of 3125 (the R2 grid-occupancy wall).
// Partials combine through a 16KB LDS buffer; then coalesced latent stores,
// wave-0 scalar-h MLP, and pass B with thread = one gaussian streaming the
// block's 64 probes from a broadcast LDS read.
__global__ __launch_bounds__(TPB, 6) void gp_main(
    const float* __restrict__ pos, const float* __restrict__ Ct,
    const float* __restrict__ W1, const float* __restrict__ b1,
    const float* __restrict__ W2, const float* __restrict__ b2,
    float* __restrict__ sh_out, float* __restrict__ lat_out,
    float* __restrict__ w_out, int N) {
  __shared__ float part[KSPL * PPB * PSTR];  // 16 KB: [kg][probe][16]
  __shared__ float4 pxyzi[PPB];              // 1 KB: per-probe (x,y,z,inv)
  const int tid  = threadIdx.x;
  const int lane = tid & 63;                 // probe lane in pass A
  const int wv   = tid >> 6;                 // wave index == k-group
  const int pbase = blockIdx.x * PPB;

  // ---- stage probe xyz ----
  if (tid < PPB) {
    int p = pbase + tid; if (p >= N) p = N - 1;
    pxyzi[tid] = make_float4(pos[p*3+0], pos[p*3+1], pos[p*3+2], 0.f);
  }
  __syncthreads();

  const float4 pv = pxyzi[lane];
  const float x = pv.x, y = pv.y, z = pv.z;
  const float xx = x*x, yy = y*y, zz = z*z;
  const float xy = x*y, xz = x*z, yz = y*z;
  const float pp = xx + yy + zz;

  // ---- pass A: partial denom + latent over this wave's 64 gaussians ----
  // kg is wave-uniform -> coefficient reads stay on the scalar pipe.
  const int kg = __builtin_amdgcn_readfirstlane(wv);
  const float* cbase = Ct + (size_t)(kg * KPT) * 32;
  float lat[DD];
  #pragma unroll
  for (int j = 0; j < DD; ++j) lat[j] = 0.0f;
  float dsum = 0.0f;
  #pragma unroll 4
  for (int i = 0; i < KPT; ++i) {
    const float* c = cbase + (i << 5);
    float g = gauss_eval(c, xx, yy, zz, xy, xz, yz, x, y, z, pp);
    dsum += g;
    #pragma unroll
    for (int j = 0; j < DD; ++j) lat[j] = fmaf(g, c[16+j], lat[j]);
  }
  {
    float* pw = part + (wv * PPB + lane) * PSTR;
    *(float4*)(pw + 0) = make_float4(lat[0], lat[1], lat[2],  lat[3]);
    *(float4*)(pw + 4) = make_float4(lat[4], lat[5], lat[6],  lat[7]);
    *(float4*)(pw + 8) = make_float4(lat[8], lat[9], lat[10], lat[11]);
    *(float4*)(pw +12) = make_float4(dsum, 0.f, 0.f, 0.f);
  }

  // pass-B coefficients: thread owns gaussian k = tid (15 live coeffs).
  // Issue the loads here so their latency hides under the barriers/reduction.
  float cb[16];
  {
    const float4* r = (const float4*)(Ct + ((size_t)tid << 5));
    *(float4*)&cb[0]  = r[0];
    *(float4*)&cb[4]  = r[1];
    *(float4*)&cb[8]  = r[2];
    *(float4*)&cb[12] = r[3];
  }
  __syncthreads();

  // ---- combine partials in place (into kg=0 slice) ----
  #pragma unroll
  for (int s = tid; s < PPB*13; s += TPB) {
    const int pr = s / 13, j = s - pr*13;
    float a = part[(0*PPB + pr)*PSTR + j] + part[(1*PPB + pr)*PSTR + j]
            + part[(2*PPB + pr)*PSTR + j] + part[(3*PPB + pr)*PSTR + j];
    part[pr*PSTR + j] = a;
  }
  __syncthreads();

  // ---- inv per probe (wave 0 keeps it in-register for the MLP) ----
  float inv = 0.0f;
  if (tid < PPB) {
    inv = 1.0f / (part[tid*PSTR + 12] + 1e-8f);
    pxyzi[tid].w = inv;
  }
  __syncthreads();

  // ---- latent store: 192 threads x float4, contiguous 3KB per block ----
  if (tid < PPB*3) {
    const int pr = tid / 3, q = tid - pr*3;
    if (pbase + pr < N) {
      const float iv = pxyzi[pr].w;
      const float* r = part + pr*PSTR + q*4;
      *(float4*)(lat_out + (size_t)pbase*DD + tid*4) =
          make_float4(r[0]*iv, r[1]*iv, r[2]*iv, r[3]*iv);
    }
  }

  // ---- fused MLP on wave 0 (scalar-h form keeps VGPR peak low) ----
  if (tid < PPB && pbase + tid < N) {
    float in15[15];
    #pragma unroll
    for (int j = 0; j < DD; ++j) in15[j] = part[tid*PSTR + j] * inv;
    in15[12] = x; in15[13] = y; in15[14] = z;
    float o[CC];
    #pragma unroll
    for (int c2 = 0; c2 < CC; ++c2) o[c2] = b2[c2];
    #pragma unroll 2
    for (int j = 0; j < HH; ++j) {
      float a = b1[j];
      #pragma unroll
      for (int i = 0; i < 15; ++i) a = fmaf(in15[i], W1[i*HH + j], a);
      a = fmaxf(a, 0.f);
      #pragma unroll
      for (int c2 = 0; c2 < CC; ++c2) o[c2] = fmaf(a, W2[j*CC + c2], o[c2]);
    }
    float* so = sh_out + (size_t)(pbase + tid) * CC;
    #pragma unroll
    for (int c2 = 0; c2 < CC; ++c2) so[c2] = o[c2];
  }

  // ---- pass B: thread = gaussian tid; stream the 64 probes ----
  // Broadcast b128 read of (x,y,z,inv); one dword store per probe; waves
  // staggered so concurrent stores spread across probe rows.
  #pragma unroll 4
  for (int pi = 0; pi < PPB; ++pi) {
    const int lp = (pi + (wv << 4)) & (PPB - 1);
    const float4 b = pxyzi[lp];
    const float bx = b.x, by = b.y, bz = b.z, binv = b.w;
    const float bxx = bx*bx, byy = by*by, bzz = bz*bz;
    const float bxy = bx*by, bxz = bx*bz, byz = by*bz;
    const float bpp = bxx + byy + bzz;
    const float wval = gauss_eval(cb, bxx, byy, bzz, bxy, bxz, byz,
                                  bx, by, bz, bpp) * binv;
    const int gp2 = pbase + lp;
    if (gp2 < N) w_out[(size_t)gp2 * KG + tid] = wval;
  }
}

extern "C" void kernel_launch(void* const* d_in, const int* in_sizes, int n_in,
                              void* d_out, int out_size, void* d_ws, size_t ws_size,
                              hipStream_t stream) {
  const float* probe_pos = (const float*)d_in[0];
  const float* mu        = (const float*)d_in[1];
  const float* log_s     = (const float*)d_in[2];
  const float* q         = (const float*)d_in[3];
  const float* F         = (const float*)d_in[4];
  const float* W1        = (const float*)d_in[5];
  const float* b1        = (const float*)d_in[6];
  const float* W2        = (const float*)d_in[7];
  const float* b2        = (const float*)d_in[8];
  const int N = in_sizes[0] / 3;

  float* Ct = (float*)d_ws;                    // 256*32 floats = 32 KB
  float* sh_out  = (float*)d_out;              // [N,9]
  float* lat_out = sh_out + (size_t)N*CC;      // [N,12]
  float* w_out   = lat_out + (size_t)N*DD;     // [N,256]

  gp_pre<<<1, 256, 0, stream>>>(mu, log_s, q, F, Ct);
  const int nb = (N + PPB - 1) / PPB;
  gp_main<<<nb, TPB, 0, stream>>>(probe_pos, Ct, W1, b1, W2, b2,
                                  sh_out, lat_out, w_out, N);
}